// Round 6
// baseline (850.262 us; speedup 1.0000x reference)
//
#include <hip/hip_runtime.h>
#include <stdint.h>

typedef __attribute__((ext_vector_type(8))) short s16x8;
typedef __attribute__((ext_vector_type(4))) float f32x4;

#define DEVFN static __device__ __forceinline__

constexpr int   S_LEN = 2048;   // sequence length n
constexpr int   DH    = 128;    // head dim
constexpr int   INNER = 2048;   // heads*dim_head
constexpr float ASCALE = 0.08838834764831845f;  // 128^-0.5

DEVFN float b2f(unsigned short u) {
  union { unsigned int i; float f; } v; v.i = ((unsigned int)u) << 16; return v.f;
}
DEVFN unsigned short f2b(float f) {
  union { float f; unsigned int i; } v; v.f = f;
  unsigned int r = v.i + 0x7fffu + ((v.i >> 16) & 1u);
  return (unsigned short)(r >> 16);
}
DEVFN void async_cp16(const unsigned short* g, unsigned short* l) {
  __builtin_amdgcn_global_load_lds((const __attribute__((address_space(1))) void*)g,
                                   (__attribute__((address_space(3))) void*)l, 16, 0, 0);
}

// ---------------- fp32 -> bf16 convert (8 elems/thread) ----------------
__global__ __launch_bounds__(256) void cvt_bf16_k(const float* __restrict__ in,
                                                  unsigned short* __restrict__ out) {
  const size_t e = ((size_t)blockIdx.x * 256 + threadIdx.x) * 8;
  const float4 a = *(const float4*)(in + e);
  const float4 b = *(const float4*)(in + e + 4);
  union { s16x8 v; unsigned short u[8]; } o;
  o.u[0] = f2b(a.x); o.u[1] = f2b(a.y); o.u[2] = f2b(a.z); o.u[3] = f2b(a.w);
  o.u[4] = f2b(b.x); o.u[5] = f2b(b.y); o.u[6] = f2b(b.z); o.u[7] = f2b(b.w);
  *(s16x8*)(out + e) = o.v;
}

// ---------------- transpose + convert (fp32 in, bf16 out, 64x64 tiles) -----
__global__ __launch_bounds__(256) void transpose_cvt_k(const float* __restrict__ in,
                                                       unsigned short* __restrict__ out,
                                                       int R, int C) {
  __shared__ __align__(16) unsigned short tile[64][72];
  const int t  = threadIdx.x;
  const int lr = t >> 3;          // 0..31
  const int lc = (t & 7) << 3;    // 0..56
  const size_t ibase = (size_t)blockIdx.y * 64 * C + (size_t)blockIdx.x * 64;
#pragma unroll
  for (int rr = 0; rr < 64; rr += 32) {
    const float* p = in + ibase + (size_t)(rr + lr) * C + lc;
    const float4 a = *(const float4*)p;
    const float4 b = *(const float4*)(p + 4);
    unsigned short* tp = &tile[rr + lr][lc];
    tp[0] = f2b(a.x); tp[1] = f2b(a.y); tp[2] = f2b(a.z); tp[3] = f2b(a.w);
    tp[4] = f2b(b.x); tp[5] = f2b(b.y); tp[6] = f2b(b.z); tp[7] = f2b(b.w);
  }
  __syncthreads();
  const size_t obase = (size_t)blockIdx.x * 64 * R + (size_t)blockIdx.y * 64;
#pragma unroll
  for (int rr = 0; rr < 64; rr += 32) {
    int oc = rr + lr;
    union { s16x8 v; unsigned short s[8]; } u;
#pragma unroll
    for (int j = 0; j < 8; ++j) u.s[j] = tile[lc + j][oc];
    *(s16x8*)(out + obase + (size_t)oc * R + lc) = u.v;
  }
}

// ---------------- bt-GEMM: C[m][n] = sum_k A[m][k] * Bt[n][k] ----------------
// EPI 0: qkv scatter (q,k -> (b,h,n,d); v -> (b,h,d,n)), bf16 outs
// EPI 1: outf = C + biasf, row-major (M,N) fp32
template <int EPI>
__global__ __launch_bounds__(256) void gemm_bt(
    const unsigned short* __restrict__ A,
    const unsigned short* __restrict__ Bt,
    unsigned short* __restrict__ out0,
    unsigned short* __restrict__ out1,
    unsigned short* __restrict__ out2,
    float* __restrict__ outf,
    const float* __restrict__ biasf,
    int M, int N, int K) {
  __shared__ __align__(16) unsigned short As[128 * 64];
  __shared__ __align__(16) unsigned short Bs[128 * 64];
  const int tid  = threadIdx.x;
  const int wave = tid >> 6, lane = tid & 63;
  const int wm = wave & 1, wn = wave >> 1;
  const int quad = lane >> 4, l15 = lane & 15;
  const int m0 = blockIdx.x * 128, n0 = blockIdx.y * 128;

  f32x4 acc[4][4];
#pragma unroll
  for (int i = 0; i < 4; ++i)
#pragma unroll
    for (int j = 0; j < 4; ++j) acc[i][j] = {0.f, 0.f, 0.f, 0.f};

  const unsigned short* a_g = A  + (size_t)(m0 + wave * 32 + (lane >> 3)) * K + ((lane & 7) << 3);
  const unsigned short* b_g = Bt + (size_t)(n0 + wave * 32 + (lane >> 3)) * K + ((lane & 7) << 3);
  unsigned short* As_w = As + (wave * 32) * 64;
  unsigned short* Bs_w = Bs + (wave * 32) * 64;

  for (int k0 = 0; k0 < K; k0 += 64) {
    __syncthreads();
#pragma unroll
    for (int t = 0; t < 4; ++t) {
      async_cp16(a_g + k0 + (size_t)(t * 8) * K, As_w + t * 8 * 64);
      async_cp16(b_g + k0 + (size_t)(t * 8) * K, Bs_w + t * 8 * 64);
    }
    __syncthreads();
#pragma unroll
    for (int ks = 0; ks < 2; ++ks) {
      s16x8 af[4], bfr[4];
#pragma unroll
      for (int mi = 0; mi < 4; ++mi)
        af[mi] = *(const s16x8*)(As + (wm * 64 + mi * 16 + l15) * 64 + ks * 32 + quad * 8);
#pragma unroll
      for (int ni = 0; ni < 4; ++ni)
        bfr[ni] = *(const s16x8*)(Bs + (wn * 64 + ni * 16 + l15) * 64 + ks * 32 + quad * 8);
#pragma unroll
      for (int mi = 0; mi < 4; ++mi)
#pragma unroll
        for (int ni = 0; ni < 4; ++ni)
          acc[mi][ni] = __builtin_amdgcn_mfma_f32_16x16x32_bf16(af[mi], bfr[ni], acc[mi][ni], 0, 0, 0);
    }
  }

#pragma unroll
  for (int mi = 0; mi < 4; ++mi)
#pragma unroll
    for (int ni = 0; ni < 4; ++ni)
#pragma unroll
      for (int r = 0; r < 4; ++r) {
        const int gm = m0 + wm * 64 + mi * 16 + quad * 4 + r;
        const int gn = n0 + wn * 64 + ni * 16 + l15;
        const float v = acc[mi][ni][r];
        if constexpr (EPI == 0) {
          const int b = gm >> 11, i = gm & 2047;   // M rows = b*2048 + i
          if (gn < INNER) {
            const int h = gn >> 7, dd = gn & 127;
            out0[((size_t)((b << 4) + h) * S_LEN + i) * DH + dd] = f2b(v);
          } else if (gn < 2 * INNER) {
            const int g = gn - INNER, h = g >> 7, dd = g & 127;
            out1[((size_t)((b << 4) + h) * S_LEN + i) * DH + dd] = f2b(v);
          } else {
            const int g = gn - 2 * INNER, h = g >> 7, dd = g & 127;
            out2[((size_t)((b << 4) + h) * DH + dd) * S_LEN + i] = f2b(v);
          }
        } else {
          outf[(size_t)gm * N + gn] = v + biasf[gn];
        }
      }
}

// ---------------- rotary (in-place on q and k, q also scaled) ----------------
__global__ __launch_bounds__(256) void rotary_qk(unsigned short* __restrict__ q,
                                                 unsigned short* __restrict__ k,
                                                 const float* __restrict__ rot) {
  const size_t e = ((size_t)blockIdx.x * 256 + threadIdx.x) * 8;
  const int dd = (int)(e & 127);
  const int i  = (int)((e >> 7) & 2047);
  union { s16x8 v; unsigned short u[8]; } qv, kv;
  const float* rp = rot + (size_t)i * 128 + dd;
  const float4 r0 = *(const float4*)rp;
  const float4 r1 = *(const float4*)(rp + 4);
  const float f[8] = {r0.x, r0.y, r0.z, r0.w, r1.x, r1.y, r1.z, r1.w};
  qv.v = *(const s16x8*)(q + e);
  kv.v = *(const s16x8*)(k + e);
  float c[8], s[8];
#pragma unroll
  for (int j = 0; j < 8; ++j) { c[j] = __cosf(f[j]); s[j] = __sinf(f[j]); }
#pragma unroll
  for (int p = 0; p < 4; ++p) {
    const float q0 = b2f(qv.u[2 * p]), q1 = b2f(qv.u[2 * p + 1]);
    const float k0 = b2f(kv.u[2 * p]), k1 = b2f(kv.u[2 * p + 1]);
    qv.u[2 * p]     = f2b((q0 * c[2 * p]     - q1 * s[2 * p])     * ASCALE);
    qv.u[2 * p + 1] = f2b((q1 * c[2 * p + 1] + q0 * s[2 * p + 1]) * ASCALE);
    kv.u[2 * p]     = f2b(k0 * c[2 * p]     - k1 * s[2 * p]);
    kv.u[2 * p + 1] = f2b(k1 * c[2 * p + 1] + k0 * s[2 * p + 1]);
  }
  *(s16x8*)(q + e) = qv.v;
  *(s16x8*)(k + e) = kv.v;
}

// ---------------- flash attention --------------------------------------
// 128-thread blocks (2 waves), 32 Q-rows/wave (2 m-tiles), K-tile 64.
// Swizzled LDS, streaming softmax, private per-wave P (no 3rd barrier),
// register prefetch of next K/V tile overlapping the whole compute body.
// grid (S/64, B*H). q,k: (b,h,n,d); vt: (b,h,d,n). out: (b,n,h*d) bf16
__global__ __launch_bounds__(128, 2) void flash_attn(
    const unsigned short* __restrict__ q,
    const unsigned short* __restrict__ k,
    const unsigned short* __restrict__ vt,
    unsigned short* __restrict__ aout) {
  __shared__ __align__(16) unsigned short Ks[64 * 128];   // 16 KB swz
  __shared__ __align__(16) unsigned short Vs[128 * 64];   // 16 KB swz
  __shared__ __align__(16) unsigned short Ps[2][32 * 64]; //  8 KB, per-wave
  const int tid = threadIdx.x;
  const int w = tid >> 6, lane = tid & 63;
  const int quad = lane >> 4, l15 = lane & 15;
  const int l7 = l15 & 7;
  const int i0 = blockIdx.x * 64;
  const int bh = blockIdx.y;
  const unsigned short* qh = q  + (size_t)bh * S_LEN * DH;
  const unsigned short* kh = k  + (size_t)bh * S_LEN * DH;
  const unsigned short* vh = vt + (size_t)bh * DH * S_LEN;

  // Q fragments: 2 m-tiles (rows i0 + w*32 + mi*16 + l15)
  s16x8 qf[2][4];
#pragma unroll
  for (int mi = 0; mi < 2; ++mi)
#pragma unroll
    for (int ks = 0; ks < 4; ++ks)
      qf[mi][ks] = *(const s16x8*)(qh + (size_t)(i0 + w * 32 + mi * 16 + l15) * DH + ks * 32 + quad * 8);

  f32x4 oacc[2][8];
#pragma unroll
  for (int mi = 0; mi < 2; ++mi)
#pragma unroll
    for (int ni = 0; ni < 8; ++ni) oacc[mi][ni] = {0.f, 0.f, 0.f, 0.f};
  float lpart[2][4];
#pragma unroll
  for (int mi = 0; mi < 2; ++mi)
#pragma unroll
    for (int r = 0; r < 4; ++r) lpart[mi][r] = 0.f;

  unsigned short* Pw = Ps[w];   // private 32x64 swz slice

  // register prefetch buffers: K 64x128 + Vt 128x64, 8 steps each (128 thr)
  s16x8 pk[8], pv[8];
#pragma unroll
  for (int v = 0; v < 8; ++v) {
    const int off = v * 1024 + tid * 8;
    pk[v] = *(const s16x8*)(kh + (size_t)(off >> 7) * DH + (off & 127));
    pv[v] = *(const s16x8*)(vh + (size_t)(off >> 6) * S_LEN + (off & 63));
  }

  for (int j0 = 0; j0 < S_LEN; j0 += 64) {
    __syncthreads();   // prev iter's LDS reads complete
    // regs -> LDS (swizzled chunk ^ (row&7))
#pragma unroll
    for (int v = 0; v < 8; ++v) {
      const int off = v * 1024 + tid * 8;
      const int kr = off >> 7, kc = off & 127;
      *(s16x8*)(Ks + kr * 128 + ((((kc >> 3) ^ (kr & 7))) << 3)) = pk[v];
      const int vr = off >> 6, vc = off & 63;
      *(s16x8*)(Vs + vr * 64 + ((((vc >> 3) ^ (vr & 7))) << 3)) = pv[v];
    }
    __syncthreads();

    // prefetch next tile (overlaps QK+softmax+PV below)
    if (j0 + 64 < S_LEN) {
#pragma unroll
      for (int v = 0; v < 8; ++v) {
        const int off = v * 1024 + tid * 8;
        pk[v] = *(const s16x8*)(kh + (size_t)(j0 + 64 + (off >> 7)) * DH + (off & 127));
        pv[v] = *(const s16x8*)(vh + (size_t)(off >> 6) * S_LEN + j0 + 64 + (off & 63));
      }
    }

    // S = q @ K^T (2 m-tiles x 4 n-tiles; kb shared across m)
    f32x4 sacc[2][4];
#pragma unroll
    for (int mi = 0; mi < 2; ++mi)
#pragma unroll
      for (int ni = 0; ni < 4; ++ni) sacc[mi][ni] = {0.f, 0.f, 0.f, 0.f};
#pragma unroll
    for (int ks = 0; ks < 4; ++ks) {
      s16x8 kb[4];
#pragma unroll
      for (int ni = 0; ni < 4; ++ni)
        kb[ni] = *(const s16x8*)(Ks + (ni * 16 + l15) * 128 + (((ks * 4 + quad) ^ l7) << 3));
#pragma unroll
      for (int mi = 0; mi < 2; ++mi)
#pragma unroll
        for (int ni = 0; ni < 4; ++ni)
          sacc[mi][ni] = __builtin_amdgcn_mfma_f32_16x16x32_bf16(qf[mi][ks], kb[ni], sacc[mi][ni], 0, 0, 0);
    }

    // streaming softmax: p = exp(min(S,40)); per-lane partial row sums
#pragma unroll
    for (int mi = 0; mi < 2; ++mi)
#pragma unroll
      for (int ni = 0; ni < 4; ++ni)
#pragma unroll
        for (int r = 0; r < 4; ++r) {
          const float p = __expf(fminf(sacc[mi][ni][r], 40.f));
          sacc[mi][ni][r] = p;
          lpart[mi][r] += p;
        }

    // P -> private LDS slice (swizzled); no block barrier needed
#pragma unroll
    for (int mi = 0; mi < 2; ++mi)
#pragma unroll
      for (int ni = 0; ni < 4; ++ni) {
        const int col = ni * 16 + l15;
        const int ch  = col >> 3;
#pragma unroll
        for (int r = 0; r < 4; ++r) {
          const int row = mi * 16 + quad * 4 + r;
          Pw[row * 64 + ((ch ^ (row & 7)) << 3) + (col & 7)] = f2b(sacc[mi][ni][r]);
        }
      }
    __threadfence_block();  // wave-local P write -> read ordering

    // O += P @ V (vb shared across m-tiles)
#pragma unroll
    for (int ks = 0; ks < 2; ++ks) {
      const int swz = ((ks * 4 + quad) ^ l7) << 3;
      s16x8 pf[2];
#pragma unroll
      for (int mi = 0; mi < 2; ++mi)
        pf[mi] = *(const s16x8*)(Pw + (mi * 16 + l15) * 64 + swz);
#pragma unroll
      for (int ni = 0; ni < 8; ++ni) {
        s16x8 vb = *(const s16x8*)(Vs + (ni * 16 + l15) * 64 + swz);
#pragma unroll
        for (int mi = 0; mi < 2; ++mi)
          oacc[mi][ni] = __builtin_amdgcn_mfma_f32_16x16x32_bf16(pf[mi], vb, oacc[mi][ni], 0, 0, 0);
      }
    }
  }

  const int b = bh >> 4, h = bh & 15;
#pragma unroll
  for (int mi = 0; mi < 2; ++mi)
#pragma unroll
    for (int r = 0; r < 4; ++r) {
      float s0 = lpart[mi][r];
      s0 += __shfl_xor(s0, 1);
      s0 += __shfl_xor(s0, 2);
      s0 += __shfl_xor(s0, 4);
      s0 += __shfl_xor(s0, 8);
      const float inv = 1.0f / s0;
      const int i = i0 + w * 32 + mi * 16 + quad * 4 + r;
#pragma unroll
      for (int ni = 0; ni < 8; ++ni) {
        const int dd = ni * 16 + l15;
        aout[((size_t)b * S_LEN + i) * INNER + h * DH + dd] = f2b(oacc[mi][ni][r] * inv);
      }
    }
}

// ---------------- host ----------------
extern "C" void kernel_launch(void* const* d_in, const int* in_sizes, int n_in,
                              void* d_out, int out_size, void* d_ws, size_t ws_size,
                              hipStream_t stream) {
  const float* x   = (const float*)d_in[0];  // (2,2048,2048) fp32
  const float* rot = (const float*)d_in[1];  // (2048,128)    fp32
  const float* Wq  = (const float*)d_in[2];  // (2048,2048)   fp32
  const float* Wkv = (const float*)d_in[3];  // (2048,4096)   fp32
  const float* Wo  = (const float*)d_in[4];  // (2048,2048)   fp32
  const float* bo  = (const float*)d_in[5];  // (2048,)       fp32
  float* out = (float*)d_out;                // (2,2048,2048) fp32

  unsigned short* ws = (unsigned short*)d_ws;
  unsigned short* wt  = ws;                                    // (6144,2048) = Wq^T | Wkv^T bf16
  unsigned short* wot = wt  + (size_t)6144 * 2048;             // (2048,2048) = Wo^T bf16
  unsigned short* qb  = wot + (size_t)2048 * 2048;             // (2,16,2048,128) bf16
  unsigned short* kb  = qb  + (size_t)32 * 2048 * 128;
  unsigned short* vtb = kb  + (size_t)32 * 2048 * 128;         // (2,16,128,2048) bf16
  unsigned short* xb  = vtb + (size_t)32 * 2048 * 128;         // (4096,2048) bf16 copy of x
  unsigned short* att = wt;                                    // reuse: (4096, 2048) bf16

  cvt_bf16_k<<<dim3(4096), 256, 0, stream>>>(x, xb);
  transpose_cvt_k<<<dim3(32, 32), 256, 0, stream>>>(Wq,  wt, 2048, 2048);
  transpose_cvt_k<<<dim3(64, 32), 256, 0, stream>>>(Wkv, wt + (size_t)2048 * 2048, 2048, 4096);
  transpose_cvt_k<<<dim3(32, 32), 256, 0, stream>>>(Wo,  wot, 2048, 2048);

  gemm_bt<0><<<dim3(32, 48), 256, 0, stream>>>(xb, wt, qb, kb, vtb, nullptr, nullptr, 4096, 6144, 2048);
  rotary_qk<<<dim3(4096), 256, 0, stream>>>(qb, kb, rot);
  flash_attn<<<dim3(32, 32), 128, 0, stream>>>(qb, kb, vtb, att);
  gemm_bt<1><<<dim3(32, 16), 256, 0, stream>>>(att, wot, nullptr, nullptr, nullptr, out, bo, 4096, 2048, 2048);
}

// Round 7
// 517.690 us; speedup vs baseline: 1.6424x; 1.6424x over previous
//
#include <hip/hip_runtime.h>
#include <stdint.h>

typedef __attribute__((ext_vector_type(8))) short s16x8;
typedef __attribute__((ext_vector_type(4))) float f32x4;

#define DEVFN static __device__ __forceinline__

constexpr int   S_LEN = 2048;   // sequence length n
constexpr int   DH    = 128;    // head dim
constexpr int   INNER = 2048;   // heads*dim_head
constexpr float ASCALE = 0.08838834764831845f;  // 128^-0.5

DEVFN float b2f(unsigned short u) {
  union { unsigned int i; float f; } v; v.i = ((unsigned int)u) << 16; return v.f;
}
DEVFN unsigned short f2b(float f) {
  union { float f; unsigned int i; } v; v.f = f;
  unsigned int r = v.i + 0x7fffu + ((v.i >> 16) & 1u);
  return (unsigned short)(r >> 16);
}
DEVFN void async_cp16(const unsigned short* g, unsigned short* l) {
  __builtin_amdgcn_global_load_lds((const __attribute__((address_space(1))) void*)g,
                                   (__attribute__((address_space(3))) void*)l, 16, 0, 0);
}

// ---------------- fp32 -> bf16 convert (8 elems/thread) ----------------
__global__ __launch_bounds__(256) void cvt_bf16_k(const float* __restrict__ in,
                                                  unsigned short* __restrict__ out) {
  const size_t e = ((size_t)blockIdx.x * 256 + threadIdx.x) * 8;
  const float4 a = *(const float4*)(in + e);
  const float4 b = *(const float4*)(in + e + 4);
  union { s16x8 v; unsigned short u[8]; } o;
  o.u[0] = f2b(a.x); o.u[1] = f2b(a.y); o.u[2] = f2b(a.z); o.u[3] = f2b(a.w);
  o.u[4] = f2b(b.x); o.u[5] = f2b(b.y); o.u[6] = f2b(b.z); o.u[7] = f2b(b.w);
  *(s16x8*)(out + e) = o.v;
}

// ---------------- transpose + convert (fp32 in, bf16 out, 64x64 tiles) -----
__global__ __launch_bounds__(256) void transpose_cvt_k(const float* __restrict__ in,
                                                       unsigned short* __restrict__ out,
                                                       int R, int C) {
  __shared__ __align__(16) unsigned short tile[64][72];
  const int t  = threadIdx.x;
  const int lr = t >> 3;          // 0..31
  const int lc = (t & 7) << 3;    // 0..56
  const size_t ibase = (size_t)blockIdx.y * 64 * C + (size_t)blockIdx.x * 64;
#pragma unroll
  for (int rr = 0; rr < 64; rr += 32) {
    const float* p = in + ibase + (size_t)(rr + lr) * C + lc;
    const float4 a = *(const float4*)p;
    const float4 b = *(const float4*)(p + 4);
    unsigned short* tp = &tile[rr + lr][lc];
    tp[0] = f2b(a.x); tp[1] = f2b(a.y); tp[2] = f2b(a.z); tp[3] = f2b(a.w);
    tp[4] = f2b(b.x); tp[5] = f2b(b.y); tp[6] = f2b(b.z); tp[7] = f2b(b.w);
  }
  __syncthreads();
  const size_t obase = (size_t)blockIdx.x * 64 * R + (size_t)blockIdx.y * 64;
#pragma unroll
  for (int rr = 0; rr < 64; rr += 32) {
    int oc = rr + lr;
    union { s16x8 v; unsigned short s[8]; } u;
#pragma unroll
    for (int j = 0; j < 8; ++j) u.s[j] = tile[lc + j][oc];
    *(s16x8*)(out + obase + (size_t)oc * R + lc) = u.v;
  }
}

// ---------------- bt-GEMM: C[m][n] = sum_k A[m][k] * Bt[n][k] ----------------
// EPI 0: qkv scatter with FUSED ROTARY on q,k (q,k -> (b,h,n,d); v -> (b,h,d,n))
// EPI 1: outf = C + biasf, row-major (M,N) fp32
template <int EPI>
__global__ __launch_bounds__(256) void gemm_bt(
    const unsigned short* __restrict__ A,
    const unsigned short* __restrict__ Bt,
    unsigned short* __restrict__ out0,
    unsigned short* __restrict__ out1,
    unsigned short* __restrict__ out2,
    float* __restrict__ outf,
    const float* __restrict__ biasf,
    const float* __restrict__ rot,
    int M, int N, int K) {
  __shared__ __align__(16) unsigned short As[128 * 64];
  __shared__ __align__(16) unsigned short Bs[128 * 64];
  const int tid  = threadIdx.x;
  const int wave = tid >> 6, lane = tid & 63;
  const int wm = wave & 1, wn = wave >> 1;
  const int quad = lane >> 4, l15 = lane & 15;
  const int m0 = blockIdx.x * 128, n0 = blockIdx.y * 128;

  f32x4 acc[4][4];
#pragma unroll
  for (int i = 0; i < 4; ++i)
#pragma unroll
    for (int j = 0; j < 4; ++j) acc[i][j] = {0.f, 0.f, 0.f, 0.f};

  const unsigned short* a_g = A  + (size_t)(m0 + wave * 32 + (lane >> 3)) * K + ((lane & 7) << 3);
  const unsigned short* b_g = Bt + (size_t)(n0 + wave * 32 + (lane >> 3)) * K + ((lane & 7) << 3);
  unsigned short* As_w = As + (wave * 32) * 64;
  unsigned short* Bs_w = Bs + (wave * 32) * 64;

  for (int k0 = 0; k0 < K; k0 += 64) {
    __syncthreads();
#pragma unroll
    for (int t = 0; t < 4; ++t) {
      async_cp16(a_g + k0 + (size_t)(t * 8) * K, As_w + t * 8 * 64);
      async_cp16(b_g + k0 + (size_t)(t * 8) * K, Bs_w + t * 8 * 64);
    }
    __syncthreads();
#pragma unroll
    for (int ks = 0; ks < 2; ++ks) {
      s16x8 af[4], bfr[4];
#pragma unroll
      for (int mi = 0; mi < 4; ++mi)
        af[mi] = *(const s16x8*)(As + (wm * 64 + mi * 16 + l15) * 64 + ks * 32 + quad * 8);
#pragma unroll
      for (int ni = 0; ni < 4; ++ni)
        bfr[ni] = *(const s16x8*)(Bs + (wn * 64 + ni * 16 + l15) * 64 + ks * 32 + quad * 8);
#pragma unroll
      for (int mi = 0; mi < 4; ++mi)
#pragma unroll
        for (int ni = 0; ni < 4; ++ni)
          acc[mi][ni] = __builtin_amdgcn_mfma_f32_16x16x32_bf16(af[mi], bfr[ni], acc[mi][ni], 0, 0, 0);
    }
  }

#pragma unroll
  for (int mi = 0; mi < 4; ++mi)
#pragma unroll
    for (int ni = 0; ni < 4; ++ni)
#pragma unroll
      for (int r = 0; r < 4; ++r) {
        const int gm = m0 + wm * 64 + mi * 16 + quad * 4 + r;
        const int gn = n0 + wn * 64 + ni * 16 + l15;
        const float v = acc[mi][ni][r];
        if constexpr (EPI == 0) {
          const int b = gm >> 11, i = gm & 2047;   // M rows = b*2048 + i
          if (gn < 2 * INNER) {
            // fused rotary: partner col gn^1 == lane^1 (same row: quad unaffected)
            const int dd = gn & 127;
            const float vp = __shfl_xor(v, 1);
            const float f = rot[(size_t)i * 128 + dd];
            const float c = __cosf(f), s = __sinf(f);
            float rv = (dd & 1) ? (v * c + vp * s) : (v * c - vp * s);
            if (gn < INNER) {
              const int h = gn >> 7;
              out0[((size_t)((b << 4) + h) * S_LEN + i) * DH + dd] = f2b(rv * ASCALE);
            } else {
              const int h = (gn - INNER) >> 7;
              out1[((size_t)((b << 4) + h) * S_LEN + i) * DH + dd] = f2b(rv);
            }
          } else {
            const int g = gn - 2 * INNER, h = g >> 7, dd = g & 127;
            out2[((size_t)((b << 4) + h) * DH + dd) * S_LEN + i] = f2b(v);
          }
        } else {
          outf[(size_t)gm * N + gn] = v + biasf[gn];
        }
      }
}

// ---------------- flash attention --------------------------------------
// 256 thr (4 waves), Q-tile 128 (32 rows/wave = 2 m-tiles), K-tile 64.
// Swizzled LDS (conflict-free), private per-wave P (2 barriers/iter),
// r4-style online softmax. No register prefetch (r6 spill lesson).
// grid (S/128, B*H). q,k: (b,h,n,d); vt: (b,h,d,n). out: (b,n,h*d) bf16
__global__ __launch_bounds__(256, 2) void flash_attn(
    const unsigned short* __restrict__ q,
    const unsigned short* __restrict__ k,
    const unsigned short* __restrict__ vt,
    unsigned short* __restrict__ aout) {
  __shared__ __align__(16) unsigned short Ks[64 * 128];   // 16 KB swz
  __shared__ __align__(16) unsigned short Vs[128 * 64];   // 16 KB swz
  __shared__ __align__(16) unsigned short Ps[4][32 * 64]; // 16 KB, per-wave
  const int tid = threadIdx.x;
  const int w = tid >> 6, lane = tid & 63;
  const int quad = lane >> 4, l15 = lane & 15;
  const int l7 = l15 & 7;
  const int i0 = blockIdx.x * 128;
  const int bh = blockIdx.y;
  const unsigned short* qh = q  + (size_t)bh * S_LEN * DH;
  const unsigned short* kh = k  + (size_t)bh * S_LEN * DH;
  const unsigned short* vh = vt + (size_t)bh * DH * S_LEN;

  // Q fragments: 2 m-tiles (rows i0 + w*32 + mi*16 + l15)
  s16x8 qf[2][4];
#pragma unroll
  for (int mi = 0; mi < 2; ++mi)
#pragma unroll
    for (int ks = 0; ks < 4; ++ks)
      qf[mi][ks] = *(const s16x8*)(qh + (size_t)(i0 + w * 32 + mi * 16 + l15) * DH + ks * 32 + quad * 8);

  f32x4 oacc[2][8];
#pragma unroll
  for (int mi = 0; mi < 2; ++mi)
#pragma unroll
    for (int ni = 0; ni < 8; ++ni) oacc[mi][ni] = {0.f, 0.f, 0.f, 0.f};
  float mrun[2][4], lrun[2][4];
#pragma unroll
  for (int mi = 0; mi < 2; ++mi)
#pragma unroll
    for (int r = 0; r < 4; ++r) { mrun[mi][r] = -1e30f; lrun[mi][r] = 0.f; }

  unsigned short* Pw = Ps[w];   // private 32x64 swz slice

  for (int j0 = 0; j0 < S_LEN; j0 += 64) {
    __syncthreads();   // prev iter's Ks/Vs reads complete
    // stage K (64x128) and Vt (128x64), swizzled chunk^(row&7); 4 vec/thread
#pragma unroll
    for (int v = 0; v < 4; ++v) {
      const int off = v * 2048 + tid * 8;
      const int kr = off >> 7, kc = off & 127;
      *(s16x8*)(Ks + kr * 128 + ((((kc >> 3) ^ (kr & 7))) << 3)) =
          *(const s16x8*)(kh + (size_t)(j0 + kr) * DH + kc);
      const int vr = off >> 6, vc = off & 63;
      *(s16x8*)(Vs + vr * 64 + ((((vc >> 3) ^ (vr & 7))) << 3)) =
          *(const s16x8*)(vh + (size_t)vr * S_LEN + j0 + vc);
    }
    __syncthreads();

    // S = q @ K^T (2 m-tiles x 4 n-tiles; kb shared across m)
    f32x4 sacc[2][4];
#pragma unroll
    for (int mi = 0; mi < 2; ++mi)
#pragma unroll
      for (int ni = 0; ni < 4; ++ni) sacc[mi][ni] = {0.f, 0.f, 0.f, 0.f};
#pragma unroll
    for (int ks = 0; ks < 4; ++ks) {
      s16x8 kb[4];
#pragma unroll
      for (int ni = 0; ni < 4; ++ni)
        kb[ni] = *(const s16x8*)(Ks + (ni * 16 + l15) * 128 + (((ks * 4 + quad) ^ l7) << 3));
#pragma unroll
      for (int mi = 0; mi < 2; ++mi)
#pragma unroll
        for (int ni = 0; ni < 4; ++ni)
          sacc[mi][ni] = __builtin_amdgcn_mfma_f32_16x16x32_bf16(qf[mi][ks], kb[ni], sacc[mi][ni], 0, 0, 0);
    }

    // online softmax (row = quad*4+r per m-tile)
#pragma unroll
    for (int mi = 0; mi < 2; ++mi)
#pragma unroll
      for (int r = 0; r < 4; ++r) {
        float v = fmaxf(fmaxf(sacc[mi][0][r], sacc[mi][1][r]),
                        fmaxf(sacc[mi][2][r], sacc[mi][3][r]));
        v = fmaxf(v, __shfl_xor(v, 1));
        v = fmaxf(v, __shfl_xor(v, 2));
        v = fmaxf(v, __shfl_xor(v, 4));
        v = fmaxf(v, __shfl_xor(v, 8));
        const float mnew  = fmaxf(mrun[mi][r], v);
        const float alpha = __expf(mrun[mi][r] - mnew);
        mrun[mi][r] = mnew;
        float s0 = 0.f;
#pragma unroll
        for (int ni = 0; ni < 4; ++ni) {
          float p = __expf(sacc[mi][ni][r] - mnew);
          sacc[mi][ni][r] = p;
          s0 += p;
        }
        s0 += __shfl_xor(s0, 1);
        s0 += __shfl_xor(s0, 2);
        s0 += __shfl_xor(s0, 4);
        s0 += __shfl_xor(s0, 8);
        lrun[mi][r] = lrun[mi][r] * alpha + s0;
#pragma unroll
        for (int ni = 0; ni < 8; ++ni) oacc[mi][ni][r] *= alpha;
      }

    // P -> private LDS slice (swizzled); no block barrier needed
#pragma unroll
    for (int mi = 0; mi < 2; ++mi)
#pragma unroll
      for (int ni = 0; ni < 4; ++ni) {
        const int col = ni * 16 + l15;
        const int ch  = col >> 3;
#pragma unroll
        for (int r = 0; r < 4; ++r) {
          const int row = mi * 16 + quad * 4 + r;
          Pw[row * 64 + ((ch ^ (row & 7)) << 3) + (col & 7)] = f2b(sacc[mi][ni][r]);
        }
      }
    __threadfence_block();  // wave-local P write -> read ordering (r6-verified)

    // O += P @ V (vb shared across m-tiles)
#pragma unroll
    for (int ks = 0; ks < 2; ++ks) {
      const int swz = ((ks * 4 + quad) ^ l7) << 3;
      s16x8 pf[2];
#pragma unroll
      for (int mi = 0; mi < 2; ++mi)
        pf[mi] = *(const s16x8*)(Pw + (mi * 16 + l15) * 64 + swz);
#pragma unroll
      for (int ni = 0; ni < 8; ++ni) {
        s16x8 vb = *(const s16x8*)(Vs + (ni * 16 + l15) * 64 + swz);
#pragma unroll
        for (int mi = 0; mi < 2; ++mi)
          oacc[mi][ni] = __builtin_amdgcn_mfma_f32_16x16x32_bf16(pf[mi], vb, oacc[mi][ni], 0, 0, 0);
      }
    }
  }

  const int b = bh >> 4, h = bh & 15;
#pragma unroll
  for (int mi = 0; mi < 2; ++mi)
#pragma unroll
    for (int r = 0; r < 4; ++r) {
      const float inv = 1.0f / lrun[mi][r];
      const int i = i0 + w * 32 + mi * 16 + quad * 4 + r;
#pragma unroll
      for (int ni = 0; ni < 8; ++ni) {
        const int dd = ni * 16 + l15;
        aout[((size_t)b * S_LEN + i) * INNER + h * DH + dd] = f2b(oacc[mi][ni][r] * inv);
      }
    }
}

// ---------------- host ----------------
extern "C" void kernel_launch(void* const* d_in, const int* in_sizes, int n_in,
                              void* d_out, int out_size, void* d_ws, size_t ws_size,
                              hipStream_t stream) {
  const float* x   = (const float*)d_in[0];  // (2,2048,2048) fp32
  const float* rot = (const float*)d_in[1];  // (2048,128)    fp32
  const float* Wq  = (const float*)d_in[2];  // (2048,2048)   fp32
  const float* Wkv = (const float*)d_in[3];  // (2048,4096)   fp32
  const float* Wo  = (const float*)d_in[4];  // (2048,2048)   fp32
  const float* bo  = (const float*)d_in[5];  // (2048,)       fp32
  float* out = (float*)d_out;                // (2,2048,2048) fp32

  unsigned short* ws = (unsigned short*)d_ws;
  unsigned short* wt  = ws;                                    // (6144,2048) = Wq^T | Wkv^T bf16
  unsigned short* wot = wt  + (size_t)6144 * 2048;             // (2048,2048) = Wo^T bf16
  unsigned short* qb  = wot + (size_t)2048 * 2048;             // (2,16,2048,128) bf16
  unsigned short* kb  = qb  + (size_t)32 * 2048 * 128;
  unsigned short* vtb = kb  + (size_t)32 * 2048 * 128;         // (2,16,128,2048) bf16
  unsigned short* xb  = vtb + (size_t)32 * 2048 * 128;         // (4096,2048) bf16 copy of x
  unsigned short* att = wt;                                    // reuse: (4096, 2048) bf16

  cvt_bf16_k<<<dim3(4096), 256, 0, stream>>>(x, xb);
  transpose_cvt_k<<<dim3(32, 32), 256, 0, stream>>>(Wq,  wt, 2048, 2048);
  transpose_cvt_k<<<dim3(64, 32), 256, 0, stream>>>(Wkv, wt + (size_t)2048 * 2048, 2048, 4096);
  transpose_cvt_k<<<dim3(32, 32), 256, 0, stream>>>(Wo,  wot, 2048, 2048);

  gemm_bt<0><<<dim3(32, 48), 256, 0, stream>>>(xb, wt, qb, kb, vtb, nullptr, nullptr, rot, 4096, 6144, 2048);
  flash_attn<<<dim3(16, 32), 256, 0, stream>>>(qb, kb, vtb, att);
  gemm_bt<1><<<dim3(32, 16), 256, 0, stream>>>(att, wot, nullptr, nullptr, nullptr, out, bo, nullptr, 4096, 2048, 2048);
}

// Round 8
// 490.381 us; speedup vs baseline: 1.7339x; 1.0557x over previous
//
#include <hip/hip_runtime.h>
#include <stdint.h>

typedef __attribute__((ext_vector_type(8))) short s16x8;
typedef __attribute__((ext_vector_type(4))) float f32x4;

#define DEVFN static __device__ __forceinline__

constexpr int   S_LEN = 2048;   // sequence length n
constexpr int   DH    = 128;    // head dim
constexpr int   INNER = 2048;   // heads*dim_head
constexpr float ASCALE = 0.08838834764831845f;  // 128^-0.5

DEVFN float b2f(unsigned short u) {
  union { unsigned int i; float f; } v; v.i = ((unsigned int)u) << 16; return v.f;
}
DEVFN unsigned short f2b(float f) {
  union { float f; unsigned int i; } v; v.f = f;
  unsigned int r = v.i + 0x7fffu + ((v.i >> 16) & 1u);
  return (unsigned short)(r >> 16);
}
DEVFN void async_cp16(const unsigned short* g, unsigned short* l) {
  __builtin_amdgcn_global_load_lds((const __attribute__((address_space(1))) void*)g,
                                   (__attribute__((address_space(3))) void*)l, 16, 0, 0);
}

// ---------------- fp32 -> bf16 convert (8 elems/thread) ----------------
__global__ __launch_bounds__(256) void cvt_bf16_k(const float* __restrict__ in,
                                                  unsigned short* __restrict__ out) {
  const size_t e = ((size_t)blockIdx.x * 256 + threadIdx.x) * 8;
  const float4 a = *(const float4*)(in + e);
  const float4 b = *(const float4*)(in + e + 4);
  union { s16x8 v; unsigned short u[8]; } o;
  o.u[0] = f2b(a.x); o.u[1] = f2b(a.y); o.u[2] = f2b(a.z); o.u[3] = f2b(a.w);
  o.u[4] = f2b(b.x); o.u[5] = f2b(b.y); o.u[6] = f2b(b.z); o.u[7] = f2b(b.w);
  *(s16x8*)(out + e) = o.v;
}

// ---------------- transpose + convert (fp32 in, bf16 out, 64x64 tiles) -----
__global__ __launch_bounds__(256) void transpose_cvt_k(const float* __restrict__ in,
                                                       unsigned short* __restrict__ out,
                                                       int R, int C) {
  __shared__ __align__(16) unsigned short tile[64][72];
  const int t  = threadIdx.x;
  const int lr = t >> 3;          // 0..31
  const int lc = (t & 7) << 3;    // 0..56
  const size_t ibase = (size_t)blockIdx.y * 64 * C + (size_t)blockIdx.x * 64;
#pragma unroll
  for (int rr = 0; rr < 64; rr += 32) {
    const float* p = in + ibase + (size_t)(rr + lr) * C + lc;
    const float4 a = *(const float4*)p;
    const float4 b = *(const float4*)(p + 4);
    unsigned short* tp = &tile[rr + lr][lc];
    tp[0] = f2b(a.x); tp[1] = f2b(a.y); tp[2] = f2b(a.z); tp[3] = f2b(a.w);
    tp[4] = f2b(b.x); tp[5] = f2b(b.y); tp[6] = f2b(b.z); tp[7] = f2b(b.w);
  }
  __syncthreads();
  const size_t obase = (size_t)blockIdx.x * 64 * R + (size_t)blockIdx.y * 64;
#pragma unroll
  for (int rr = 0; rr < 64; rr += 32) {
    int oc = rr + lr;
    union { s16x8 v; unsigned short s[8]; } u;
#pragma unroll
    for (int j = 0; j < 8; ++j) u.s[j] = tile[lc + j][oc];
    *(s16x8*)(out + obase + (size_t)oc * R + lc) = u.v;
  }
}

// ---------------- bt-GEMM: C[m][n] = sum_k A[m][k] * Bt[n][k] ----------------
// LDS XOR-swizzle: global_load_lds forces LDS dest = base + lane*16, so we
// permute the SOURCE chunk per lane (chunk = (lane&7) ^ ((lane>>3)&7)); the
// lane-contiguous LDS image is then the swizzled layout. Fragment reads use
// physical chunk ((ks*4+quad) ^ (row&7)) -> conflict-free (2-way max).
// EPI 0: qkv scatter with FUSED ROTARY on q,k (q,k -> (b,h,n,d); v -> (b,h,d,n))
// EPI 1: outf = C + biasf, row-major (M,N) fp32
template <int EPI>
__global__ __launch_bounds__(256) void gemm_bt(
    const unsigned short* __restrict__ A,
    const unsigned short* __restrict__ Bt,
    unsigned short* __restrict__ out0,
    unsigned short* __restrict__ out1,
    unsigned short* __restrict__ out2,
    float* __restrict__ outf,
    const float* __restrict__ biasf,
    const float* __restrict__ rot,
    int M, int N, int K) {
  __shared__ __align__(16) unsigned short As[128 * 64];
  __shared__ __align__(16) unsigned short Bs[128 * 64];
  const int tid  = threadIdx.x;
  const int wave = tid >> 6, lane = tid & 63;
  const int wm = wave & 1, wn = wave >> 1;
  const int quad = lane >> 4, l15 = lane & 15;
  const int l7 = l15 & 7;
  const int m0 = blockIdx.x * 128, n0 = blockIdx.y * 128;

  f32x4 acc[4][4];
#pragma unroll
  for (int i = 0; i < 4; ++i)
#pragma unroll
    for (int j = 0; j < 4; ++j) acc[i][j] = {0.f, 0.f, 0.f, 0.f};

  const int lrow = lane >> 3;                      // 0..7 (row within 8-row step)
  const int lchk = (lane & 7) ^ (lrow & 7);        // permuted source chunk
  const unsigned short* a_g = A  + (size_t)(m0 + wave * 32 + lrow) * K + (lchk << 3);
  const unsigned short* b_g = Bt + (size_t)(n0 + wave * 32 + lrow) * K + (lchk << 3);
  unsigned short* As_w = As + (wave * 32) * 64;
  unsigned short* Bs_w = Bs + (wave * 32) * 64;

  for (int k0 = 0; k0 < K; k0 += 64) {
    __syncthreads();
#pragma unroll
    for (int t = 0; t < 4; ++t) {
      async_cp16(a_g + k0 + (size_t)(t * 8) * K, As_w + t * 8 * 64);
      async_cp16(b_g + k0 + (size_t)(t * 8) * K, Bs_w + t * 8 * 64);
    }
    __syncthreads();
#pragma unroll
    for (int ks = 0; ks < 2; ++ks) {
      s16x8 af[4], bfr[4];
#pragma unroll
      for (int mi = 0; mi < 4; ++mi)
        af[mi] = *(const s16x8*)(As + (wm * 64 + mi * 16 + l15) * 64 + (((ks * 4 + quad) ^ l7) << 3));
#pragma unroll
      for (int ni = 0; ni < 4; ++ni)
        bfr[ni] = *(const s16x8*)(Bs + (wn * 64 + ni * 16 + l15) * 64 + (((ks * 4 + quad) ^ l7) << 3));
#pragma unroll
      for (int mi = 0; mi < 4; ++mi)
#pragma unroll
        for (int ni = 0; ni < 4; ++ni)
          acc[mi][ni] = __builtin_amdgcn_mfma_f32_16x16x32_bf16(af[mi], bfr[ni], acc[mi][ni], 0, 0, 0);
    }
  }

#pragma unroll
  for (int mi = 0; mi < 4; ++mi)
#pragma unroll
    for (int ni = 0; ni < 4; ++ni)
#pragma unroll
      for (int r = 0; r < 4; ++r) {
        const int gm = m0 + wm * 64 + mi * 16 + quad * 4 + r;
        const int gn = n0 + wn * 64 + ni * 16 + l15;
        const float v = acc[mi][ni][r];
        if constexpr (EPI == 0) {
          const int b = gm >> 11, i = gm & 2047;   // M rows = b*2048 + i
          if (gn < 2 * INNER) {
            // fused rotary: partner col gn^1 == lane^1 (same row: quad unaffected)
            const int dd = gn & 127;
            const float vp = __shfl_xor(v, 1);
            const float f = rot[(size_t)i * 128 + dd];
            const float c = __cosf(f), s = __sinf(f);
            float rv = (dd & 1) ? (v * c + vp * s) : (v * c - vp * s);
            if (gn < INNER) {
              const int h = gn >> 7;
              out0[((size_t)((b << 4) + h) * S_LEN + i) * DH + dd] = f2b(rv * ASCALE);
            } else {
              const int h = (gn - INNER) >> 7;
              out1[((size_t)((b << 4) + h) * S_LEN + i) * DH + dd] = f2b(rv);
            }
          } else {
            const int g = gn - 2 * INNER, h = g >> 7, dd = g & 127;
            out2[((size_t)((b << 4) + h) * DH + dd) * S_LEN + i] = f2b(v);
          }
        } else {
          outf[(size_t)gm * N + gn] = v + biasf[gn];
        }
      }
}

// ---------------- flash attention --------------------------------------
// 256 thr (4 waves), Q-tile 128 (32 rows/wave = 2 m-tiles), K-tile 64.
// Swizzled LDS (conflict-free), private per-wave P (2 barriers/iter),
// r4-style online softmax. No register prefetch (r6 spill lesson).
// grid (S/128, B*H). q,k: (b,h,n,d); vt: (b,h,d,n). out: (b,n,h*d) bf16
__global__ __launch_bounds__(256, 2) void flash_attn(
    const unsigned short* __restrict__ q,
    const unsigned short* __restrict__ k,
    const unsigned short* __restrict__ vt,
    unsigned short* __restrict__ aout) {
  __shared__ __align__(16) unsigned short Ks[64 * 128];   // 16 KB swz
  __shared__ __align__(16) unsigned short Vs[128 * 64];   // 16 KB swz
  __shared__ __align__(16) unsigned short Ps[4][32 * 64]; // 16 KB, per-wave
  const int tid = threadIdx.x;
  const int w = tid >> 6, lane = tid & 63;
  const int quad = lane >> 4, l15 = lane & 15;
  const int l7 = l15 & 7;
  const int i0 = blockIdx.x * 128;
  const int bh = blockIdx.y;
  const unsigned short* qh = q  + (size_t)bh * S_LEN * DH;
  const unsigned short* kh = k  + (size_t)bh * S_LEN * DH;
  const unsigned short* vh = vt + (size_t)bh * DH * S_LEN;

  // Q fragments: 2 m-tiles (rows i0 + w*32 + mi*16 + l15)
  s16x8 qf[2][4];
#pragma unroll
  for (int mi = 0; mi < 2; ++mi)
#pragma unroll
    for (int ks = 0; ks < 4; ++ks)
      qf[mi][ks] = *(const s16x8*)(qh + (size_t)(i0 + w * 32 + mi * 16 + l15) * DH + ks * 32 + quad * 8);

  f32x4 oacc[2][8];
#pragma unroll
  for (int mi = 0; mi < 2; ++mi)
#pragma unroll
    for (int ni = 0; ni < 8; ++ni) oacc[mi][ni] = {0.f, 0.f, 0.f, 0.f};
  float mrun[2][4], lrun[2][4];
#pragma unroll
  for (int mi = 0; mi < 2; ++mi)
#pragma unroll
    for (int r = 0; r < 4; ++r) { mrun[mi][r] = -1e30f; lrun[mi][r] = 0.f; }

  unsigned short* Pw = Ps[w];   // private 32x64 swz slice

  for (int j0 = 0; j0 < S_LEN; j0 += 64) {
    __syncthreads();   // prev iter's Ks/Vs reads complete
    // stage K (64x128) and Vt (128x64), swizzled chunk^(row&7); 4 vec/thread
#pragma unroll
    for (int v = 0; v < 4; ++v) {
      const int off = v * 2048 + tid * 8;
      const int kr = off >> 7, kc = off & 127;
      *(s16x8*)(Ks + kr * 128 + ((((kc >> 3) ^ (kr & 7))) << 3)) =
          *(const s16x8*)(kh + (size_t)(j0 + kr) * DH + kc);
      const int vr = off >> 6, vc = off & 63;
      *(s16x8*)(Vs + vr * 64 + ((((vc >> 3) ^ (vr & 7))) << 3)) =
          *(const s16x8*)(vh + (size_t)vr * S_LEN + j0 + vc);
    }
    __syncthreads();

    // S = q @ K^T (2 m-tiles x 4 n-tiles; kb shared across m)
    f32x4 sacc[2][4];
#pragma unroll
    for (int mi = 0; mi < 2; ++mi)
#pragma unroll
      for (int ni = 0; ni < 4; ++ni) sacc[mi][ni] = {0.f, 0.f, 0.f, 0.f};
#pragma unroll
    for (int ks = 0; ks < 4; ++ks) {
      s16x8 kb[4];
#pragma unroll
      for (int ni = 0; ni < 4; ++ni)
        kb[ni] = *(const s16x8*)(Ks + (ni * 16 + l15) * 128 + (((ks * 4 + quad) ^ l7) << 3));
#pragma unroll
      for (int mi = 0; mi < 2; ++mi)
#pragma unroll
        for (int ni = 0; ni < 4; ++ni)
          sacc[mi][ni] = __builtin_amdgcn_mfma_f32_16x16x32_bf16(qf[mi][ks], kb[ni], sacc[mi][ni], 0, 0, 0);
    }

    // online softmax (row = quad*4+r per m-tile)
#pragma unroll
    for (int mi = 0; mi < 2; ++mi)
#pragma unroll
      for (int r = 0; r < 4; ++r) {
        float v = fmaxf(fmaxf(sacc[mi][0][r], sacc[mi][1][r]),
                        fmaxf(sacc[mi][2][r], sacc[mi][3][r]));
        v = fmaxf(v, __shfl_xor(v, 1));
        v = fmaxf(v, __shfl_xor(v, 2));
        v = fmaxf(v, __shfl_xor(v, 4));
        v = fmaxf(v, __shfl_xor(v, 8));
        const float mnew  = fmaxf(mrun[mi][r], v);
        const float alpha = __expf(mrun[mi][r] - mnew);
        mrun[mi][r] = mnew;
        float s0 = 0.f;
#pragma unroll
        for (int ni = 0; ni < 4; ++ni) {
          float p = __expf(sacc[mi][ni][r] - mnew);
          sacc[mi][ni][r] = p;
          s0 += p;
        }
        s0 += __shfl_xor(s0, 1);
        s0 += __shfl_xor(s0, 2);
        s0 += __shfl_xor(s0, 4);
        s0 += __shfl_xor(s0, 8);
        lrun[mi][r] = lrun[mi][r] * alpha + s0;
#pragma unroll
        for (int ni = 0; ni < 8; ++ni) oacc[mi][ni][r] *= alpha;
      }

    // P -> private LDS slice (swizzled); no block barrier needed
#pragma unroll
    for (int mi = 0; mi < 2; ++mi)
#pragma unroll
      for (int ni = 0; ni < 4; ++ni) {
        const int col = ni * 16 + l15;
        const int ch  = col >> 3;
#pragma unroll
        for (int r = 0; r < 4; ++r) {
          const int row = mi * 16 + quad * 4 + r;
          Pw[row * 64 + ((ch ^ (row & 7)) << 3) + (col & 7)] = f2b(sacc[mi][ni][r]);
        }
      }
    __threadfence_block();  // wave-local P write -> read ordering (r6-verified)

    // O += P @ V (vb shared across m-tiles)
#pragma unroll
    for (int ks = 0; ks < 2; ++ks) {
      const int swz = ((ks * 4 + quad) ^ l7) << 3;
      s16x8 pf[2];
#pragma unroll
      for (int mi = 0; mi < 2; ++mi)
        pf[mi] = *(const s16x8*)(Pw + (mi * 16 + l15) * 64 + swz);
#pragma unroll
      for (int ni = 0; ni < 8; ++ni) {
        s16x8 vb = *(const s16x8*)(Vs + (ni * 16 + l15) * 64 + swz);
#pragma unroll
        for (int mi = 0; mi < 2; ++mi)
          oacc[mi][ni] = __builtin_amdgcn_mfma_f32_16x16x32_bf16(pf[mi], vb, oacc[mi][ni], 0, 0, 0);
      }
    }
  }

  const int b = bh >> 4, h = bh & 15;
#pragma unroll
  for (int mi = 0; mi < 2; ++mi)
#pragma unroll
    for (int r = 0; r < 4; ++r) {
      const float inv = 1.0f / lrun[mi][r];
      const int i = i0 + w * 32 + mi * 16 + quad * 4 + r;
#pragma unroll
      for (int ni = 0; ni < 8; ++ni) {
        const int dd = ni * 16 + l15;
        aout[((size_t)b * S_LEN + i) * INNER + h * DH + dd] = f2b(oacc[mi][ni][r] * inv);
      }
    }
}

// ---------------- host ----------------
extern "C" void kernel_launch(void* const* d_in, const int* in_sizes, int n_in,
                              void* d_out, int out_size, void* d_ws, size_t ws_size,
                              hipStream_t stream) {
  const float* x   = (const float*)d_in[0];  // (2,2048,2048) fp32
  const float* rot = (const float*)d_in[1];  // (2048,128)    fp32
  const float* Wq  = (const float*)d_in[2];  // (2048,2048)   fp32
  const float* Wkv = (const float*)d_in[3];  // (2048,4096)   fp32
  const float* Wo  = (const float*)d_in[4];  // (2048,2048)   fp32
  const float* bo  = (const float*)d_in[5];  // (2048,)       fp32
  float* out = (float*)d_out;                // (2,2048,2048) fp32

  unsigned short* ws = (unsigned short*)d_ws;
  unsigned short* wt  = ws;                                    // (6144,2048) = Wq^T | Wkv^T bf16
  unsigned short* wot = wt  + (size_t)6144 * 2048;             // (2048,2048) = Wo^T bf16
  unsigned short* qb  = wot + (size_t)2048 * 2048;             // (2,16,2048,128) bf16
  unsigned short* kb  = qb  + (size_t)32 * 2048 * 128;
  unsigned short* vtb = kb  + (size_t)32 * 2048 * 128;         // (2,16,128,2048) bf16
  unsigned short* xb  = vtb + (size_t)32 * 2048 * 128;         // (4096,2048) bf16 copy of x
  unsigned short* att = wt;                                    // reuse: (4096, 2048) bf16

  cvt_bf16_k<<<dim3(4096), 256, 0, stream>>>(x, xb);
  transpose_cvt_k<<<dim3(32, 32), 256, 0, stream>>>(Wq,  wt, 2048, 2048);
  transpose_cvt_k<<<dim3(64, 32), 256, 0, stream>>>(Wkv, wt + (size_t)2048 * 2048, 2048, 4096);
  transpose_cvt_k<<<dim3(32, 32), 256, 0, stream>>>(Wo,  wot, 2048, 2048);

  gemm_bt<0><<<dim3(32, 48), 256, 0, stream>>>(xb, wt, qb, kb, vtb, nullptr, nullptr, rot, 4096, 6144, 2048);
  flash_attn<<<dim3(16, 32), 256, 0, stream>>>(qb, kb, vtb, att);
  gemm_bt<1><<<dim3(32, 16), 256, 0, stream>>>(att, wot, nullptr, nullptr, nullptr, out, bo, nullptr, 4096, 2048, 2048);
}